// Round 2
// baseline (281.297 us; speedup 1.0000x reference)
//
#include <hip/hip_runtime.h>
#include <math.h>

#define NTOK   16384
#define DDIM   2048
#define EDIM   128
#define HDIM   128
#define TOKT   64
#define KC     32
#define NIT    32            // iterations; each handles 2 K-chunks (k-split)

typedef __attribute__((ext_vector_type(8))) _Float16 half8;
typedef __attribute__((ext_vector_type(4))) float    f32x4;

// b32-granule XOR swizzle for epilogue A[64][128]: conflict-free row+column.
__device__ __forceinline__ int swz(int t, int e) {
  return t * EDIM + ((e & 96) | ((e ^ t) & 31));
}

__device__ __forceinline__ void cvt8(const float4& a, const float4& b,
                                     half8& h, half8& l) {
#pragma unroll
  for (int m = 0; m < 4; ++m) {
    const float v = (&a.x)[m];
    const _Float16 hv = (_Float16)v;
    h[m] = hv; l[m] = (_Float16)((v - (float)hv) * 2048.0f);
  }
#pragma unroll
  for (int m = 0; m < 4; ++m) {
    const float v = (&b.x)[m];
    const _Float16 hv = (_Float16)v;
    h[m + 4] = hv; l[m + 4] = (_Float16)((v - (float)hv) * 2048.0f);
  }
}

// ---- W pre-convert: fragment-ordered f16 hi/lo planes in workspace ----
// frag idx -> (nt, ks, lane); lane holds B[k=ks*32+(lane>>4)*8+j][n=nt*16+(lane&15)]
// = Wr[n][k], scaled by 32 (hi) and 32*2048 (lo) to dodge f16 denormals.
__global__ __launch_bounds__(256)
void conv_w(const float* __restrict__ Wr,
            _Float16* __restrict__ wh, _Float16* __restrict__ wl) {
  const int idx  = (int)blockIdx.x * 256 + (int)threadIdx.x;  // 0..32767
  const int lane = idx & 63;
  const int ks   = (idx >> 6) & 63;
  const int nt   = idx >> 12;
  const int n    = nt * 16 + (lane & 15);
  const int k0   = ks * 32 + (lane >> 4) * 8;
  half8 h, l;
#pragma unroll
  for (int j = 0; j < 8; ++j) {
    const float w = Wr[(size_t)n * DDIM + k0 + j] * 32.0f;
    const _Float16 hh = (_Float16)w;
    h[j] = hh;
    l[j] = (_Float16)((w - (float)hh) * 2048.0f);
  }
  *(half8*)(wh + (size_t)idx * 8) = h;
  *(half8*)(wl + (size_t)idx * 8) = l;
}

__global__ __launch_bounds__(512, 2)
void fused_router(const float* __restrict__ x,
                  const _Float16* __restrict__ wsh,
                  const _Float16* __restrict__ wsl,
                  const float* __restrict__ Wd,
                  const float* __restrict__ gamma,
                  const float* __restrict__ beta,
                  const float* __restrict__ rnn,
                  const float* __restrict__ gum,
                  float* __restrict__ outb,
                  float* __restrict__ outa) {
  // GEMM phase: x only in LDS, fragment-ordered hi/lo f16, double-buffered:
  //   xfrag[b][kw][mt][pl][lane][8] halves -> ((b*2+kw)*4+mt)*1024 + pl*512 + lane*8
  //   (2 bufs x 16 KB = 32 KB).  W comes straight from global (frag-ordered ws).
  // Epilogue: A = bytes [0,32K), G4 = bytes [32K,64K).
  __shared__ char smraw[65536];
  _Float16* const xs = (_Float16*)smraw;
  float* const A  = (float*)smraw;
  float* const G4 = (float*)(smraw + 32768);

  const int tid  = (int)threadIdx.x;
  const int wv   = __builtin_amdgcn_readfirstlane(tid >> 6);  // 0..7
  const int lane = tid & 63;
  const int t0   = (int)blockIdx.x * TOKT;

  // wave grid: 2m x 2n x 2k. wave = 2 m-tiles x 4 n-tiles x half-K.
  const int mw   = wv & 1;
  const int nw   = (wv >> 1) & 1;
  const int kw   = wv >> 2;
  const int quad = lane >> 4;
  const int col  = lane & 15;

  // A-frag LDS read base (halves), + pb*8192 for buffer
  const int abase = (kw * 4 + mw * 2) * 1024 + lane * 8;

  // x staging: every thread owns one frag-slot (skw, smt, slane)
  const int skw   = tid >> 8;
  const int smt   = (tid >> 6) & 3;
  const int slane = tid & 63;
  const int woff  = (skw * 4 + smt) * 1024 + slane * 8;   // hi; +512 lo; +pb*8192
  const float* xg = x + (size_t)(t0 + smt * 16 + (slane & 15)) * DDIM
                      + skw * 1024 + (slane >> 4) * 8;

  // W direct-to-reg: frag offset = nt*32768 + ks*512 + lane*8, nt = nw*4+j,
  // ks = kw*32 + i
  const size_t wbase = (size_t)(nw * 4) * 32768 + (size_t)kw * 16384 + lane * 8;

  f32x4 hh[2][4], cr[2][4];
#pragma unroll
  for (int mi = 0; mi < 2; ++mi)
#pragma unroll
    for (int ni = 0; ni < 4; ++ni) { hh[mi][ni] = (f32x4){0,0,0,0}; cr[mi][ni] = (f32x4){0,0,0,0}; }

  half8 bh[2][4], bl[2][4];

  // ---- preamble: B set 0 (i=0) and x chunk-pair 0 into buffer 0 ----
#pragma unroll
  for (int j = 0; j < 4; ++j) {
    bh[0][j] = *(const half8*)(wsh + wbase + (size_t)j * 32768);
    bl[0][j] = *(const half8*)(wsl + wbase + (size_t)j * 32768);
  }
  {
    const float4 a  = *(const float4*)xg;
    const float4 b2 = *(const float4*)(xg + 4);
    half8 h, l; cvt8(a, b2, h, l);
    *(half8*)&xs[woff] = h;
    *(half8*)&xs[woff + 512] = l;
  }

  auto body = [&](int i, int pb) {
    __syncthreads();                        // buffer pb visible; pb^1 free
    const int ab = pb ? 8192 + abase : abase;
    const half8 ah0 = *(const half8*)&xs[ab];
    const half8 al0 = *(const half8*)&xs[ab + 512];
    const half8 ah1 = *(const half8*)&xs[ab + 1024];
    const half8 al1 = *(const half8*)&xs[ab + 1536];
    const int np = pb ^ 1;
    float4 pxa, pxb;
    if (i + 1 < NIT) {                      // prefetch next B frags + next x
      const size_t wo = wbase + (size_t)(i + 1) * 512;
#pragma unroll
      for (int j = 0; j < 4; ++j) {
        bh[np][j] = *(const half8*)(wsh + wo + (size_t)j * 32768);
        bl[np][j] = *(const half8*)(wsl + wo + (size_t)j * 32768);
      }
      pxa = *(const float4*)(xg + (i + 1) * KC);
      pxb = *(const float4*)(xg + (i + 1) * KC + 4);
    }
#pragma unroll
    for (int j = 0; j < 4; ++j) {
      hh[0][j] = __builtin_amdgcn_mfma_f32_16x16x32_f16(ah0, bh[pb][j], hh[0][j], 0, 0, 0);
      cr[0][j] = __builtin_amdgcn_mfma_f32_16x16x32_f16(ah0, bl[pb][j], cr[0][j], 0, 0, 0);
      cr[0][j] = __builtin_amdgcn_mfma_f32_16x16x32_f16(al0, bh[pb][j], cr[0][j], 0, 0, 0);
      hh[1][j] = __builtin_amdgcn_mfma_f32_16x16x32_f16(ah1, bh[pb][j], hh[1][j], 0, 0, 0);
      cr[1][j] = __builtin_amdgcn_mfma_f32_16x16x32_f16(ah1, bl[pb][j], cr[1][j], 0, 0, 0);
      cr[1][j] = __builtin_amdgcn_mfma_f32_16x16x32_f16(al1, bh[pb][j], cr[1][j], 0, 0, 0);
    }
    if (i + 1 < NIT) {                      // convert + write into free buffer
      half8 h, l; cvt8(pxa, pxb, h, l);
      *(half8*)&xs[np * 8192 + woff] = h;
      *(half8*)&xs[np * 8192 + woff + 512] = l;
    }
  };
  for (int ii = 0; ii < NIT; ii += 2) { body(ii, 0); body(ii + 1, 1); }
  __syncthreads();                          // GEMM LDS dead

  // ---- k-split reduce + unscale + rnn into A ----
  // C/D layout: col = lane&15 -> e, row = quad*4+r -> token
  if (kw == 0) {
#pragma unroll
    for (int mi = 0; mi < 2; ++mi)
#pragma unroll
      for (int ni = 0; ni < 4; ++ni)
#pragma unroll
        for (int r = 0; r < 4; ++r) {
          const int t = (mw * 2 + mi) * 16 + quad * 4 + r;
          const int e = (nw * 4 + ni) * 16 + col;
          A[swz(t, e)] = hh[mi][ni][r] * (1.0f / 32.0f)
                       + cr[mi][ni][r] * (1.0f / 65536.0f);
        }
  }
  __syncthreads();
  if (kw == 1) {
    float rv[4];
#pragma unroll
    for (int ni = 0; ni < 4; ++ni) rv[ni] = rnn[(nw * 4 + ni) * 16 + col];
#pragma unroll
    for (int mi = 0; mi < 2; ++mi)
#pragma unroll
      for (int ni = 0; ni < 4; ++ni)
#pragma unroll
        for (int r = 0; r < 4; ++r) {
          const int t = (mw * 2 + mi) * 16 + quad * 4 + r;
          const int e = (nw * 4 + ni) * 16 + col;
          A[swz(t, e)] += hh[mi][ni][r] * (1.0f / 32.0f)
                        + cr[mi][ni][r] * (1.0f / 65536.0f) + rv[ni];
        }
  }
  __syncthreads();

  // ---- LayerNorm + exact GELU: 8 tokens per wave; G -> G4 (float4-swizzled) ----
  {
    const float gm0 = gamma[lane], gm1 = gamma[lane + 64];
    const float bt0 = beta[lane],  bt1 = beta[lane + 64];
    for (int tt = wv * 8; tt < wv * 8 + 8; ++tt) {
      const float v0 = A[swz(tt, lane)];
      const float v1 = A[swz(tt, lane + 64)];
      float s = v0 + v1;
#pragma unroll
      for (int m = 32; m; m >>= 1) s += __shfl_xor(s, m);
      const float mu = s * (1.0f / 128.0f);
      const float d0 = v0 - mu, d1 = v1 - mu;
      float q = d0 * d0 + d1 * d1;
#pragma unroll
      for (int m = 32; m; m >>= 1) q += __shfl_xor(q, m);
      const float rstd = 1.0f / sqrtf(q * (1.0f / 128.0f) + 1e-5f);
      const float h0v = d0 * rstd * gm0 + bt0;
      const float h1v = d1 * rstd * gm1 + bt1;
      const float g0 = 0.5f * h0v * (1.0f + erff(h0v * 0.70710678118654752f));
      const float g1 = 0.5f * h1v * (1.0f + erff(h1v * 0.70710678118654752f));
      const int e0a = lane, e1a = lane + 64;
      G4[(tt * 32 + (((e0a >> 2) ^ (tt & 31)))) * 4 + (e0a & 3)] = g0;
      G4[(tt * 32 + (((e1a >> 2) ^ (tt & 31)))) * 4 + (e1a & 3)] = g1;
    }
  }
  __syncthreads();

  // ---- decoder GEMM: wave = 16 h-rows x 64 tokens (lane = token) ----
  {
    const int rbase = wv * 16;
    float acc2[16];
#pragma unroll
    for (int j = 0; j < 16; ++j) acc2[j] = 0.0f;
    const float4* wd4 = (const float4*)(Wd + (size_t)rbase * EDIM);  // uniform
#pragma unroll 2
    for (int kg = 0; kg < EDIM / 4; ++kg) {
      const float4 gv = *(const float4*)&G4[(lane * 32 + (kg ^ (lane & 31))) * 4];
#pragma unroll
      for (int j = 0; j < 16; ++j) {
        const float4 w = wd4[(size_t)j * (EDIM / 4) + kg];
        acc2[j] = fmaf(gv.x, w.x,
                  fmaf(gv.y, w.y,
                  fmaf(gv.z, w.z,
                  fmaf(gv.w, w.w, acc2[j]))));
      }
    }
#pragma unroll
    for (int j = 0; j < 16; ++j) A[swz(lane, rbase + j)] = acc2[j];
  }
  __syncthreads();

  // ---- gumbel-sigmoid, exact top-k (value then lower-index), output ----
  for (int tt = wv * 8; tt < wv * 8 + 8; ++tt) {
    const size_t T = (size_t)(t0 + tt);
    const float l0 = A[swz(tt, lane)];
    const float l1 = A[swz(tt, lane + 64)];
    const float gn0 = gum[T * HDIM + lane];
    const float gn1 = gum[T * HDIM + lane + 64];
    const float z0 = (l0 + gn0 + 3.0f) * 2.5f;
    const float z1 = (l1 + gn1 + 3.0f) * 2.5f;
    const float ba0 = 1.0f / (1.0f + expf(-z0));
    const float ba1 = 1.0f / (1.0f + expf(-z1));
    const unsigned ub0 = __float_as_uint(ba0);   // ba in (0,1]: bits monotone
    const unsigned ub1 = __float_as_uint(ba1);
    const int r0 = ba0 > 0.5f;                   // round: 0.5 -> 0
    const int r1 = ba1 > 0.5f;
    const int cnt = __popcll(__ballot(r0)) + __popcll(__ballot(r1));
    float bin0, bin1;
    if (cnt > 32) {
      unsigned v = 0u;                            // radix-select 32nd largest
#pragma unroll
      for (int b = 29; b >= 0; --b) {
        const unsigned cand = v | (1u << b);
        const int cc = __popcll(__ballot(ub0 >= cand)) + __popcll(__ballot(ub1 >= cand));
        if (cc >= 32) v = cand;
      }
      const int cgt = __popcll(__ballot(ub0 > v)) + __popcll(__ballot(ub1 > v));
      const int r = 32 - cgt;                     // tied slots; lower index wins
      const unsigned long long t0b = __ballot(ub0 == v);
      const unsigned long long t1b = __ballot(ub1 == v);
      const int n0 = __popcll(t0b);
      const unsigned long long mlt = (1ull << lane) - 1ull;
      const int rk0 = __popcll(t0b & mlt);
      const int rk1 = n0 + __popcll(t1b & mlt);
      bin0 = (ub0 > v || (ub0 == v && rk0 < r)) ? 1.0f : 0.0f;
      bin1 = (ub1 > v || (ub1 == v && rk1 < r)) ? 1.0f : 0.0f;
    } else if (cnt == 0) {
      float m = fmaxf(ba0, ba1);
#pragma unroll
      for (int mm = 32; mm; mm >>= 1) m = fmaxf(m, __shfl_xor(m, mm));
      const unsigned long long e0b = __ballot(ba0 == m);
      const unsigned long long e1b = __ballot(ba1 == m);
      const int hstar = e0b ? (__ffsll((unsigned long long)e0b) - 1)
                            : (64 + __ffsll((unsigned long long)e1b) - 1);
      bin0 = (lane == hstar) ? 1.0f : 0.0f;
      bin1 = (lane + 64 == hstar) ? 1.0f : 0.0f;
    } else {
      bin0 = r0 ? 1.0f : 0.0f;
      bin1 = r1 ? 1.0f : 0.0f;
    }
    outb[T * HDIM + lane]      = bin0;
    outb[T * HDIM + lane + 64] = bin1;
    outa[T * HDIM + lane]      = ba0;
    outa[T * HDIM + lane + 64] = ba1;
  }
}

extern "C" void kernel_launch(void* const* d_in, const int* in_sizes, int n_in,
                              void* d_out, int out_size, void* d_ws, size_t ws_size,
                              hipStream_t stream) {
  (void)in_sizes; (void)n_in; (void)ws_size; (void)out_size;
  const float* x   = (const float*)d_in[0];
  const float* Wr  = (const float*)d_in[1];
  const float* Wd  = (const float*)d_in[2];
  const float* gm  = (const float*)d_in[3];
  const float* bt  = (const float*)d_in[4];
  const float* rnn = (const float*)d_in[5];
  const float* gum = (const float*)d_in[6];
  float* outb = (float*)d_out;
  float* outa = outb + (size_t)NTOK * HDIM;   // tuple: (binary, binary_approx)

  _Float16* wh = (_Float16*)d_ws;             // 512 KB
  _Float16* wl = wh + (size_t)EDIM * DDIM;    // 512 KB

  conv_w<<<dim3(128), dim3(256), 0, stream>>>(Wr, wh, wl);
  fused_router<<<dim3(NTOK / TOKT), dim3(512), 0, stream>>>(
      x, wh, wl, Wd, gm, bt, rnn, gum, outb, outa);
}

// Round 3
// 259.395 us; speedup vs baseline: 1.0844x; 1.0844x over previous
//
#include <hip/hip_runtime.h>
#include <math.h>

#define NTOK   16384
#define DDIM   2048
#define EDIM   128
#define HDIM   128
#define TOKT   64
#define KC     32
#define NCH    64
#define BUFB   24576      // chunk buffer: A 8KB (f16 hi/lo) + B 16KB (f16 hi/lo)

typedef __attribute__((ext_vector_type(8))) _Float16 half8;
typedef __attribute__((ext_vector_type(2))) _Float16 half2v;
typedef __attribute__((ext_vector_type(4))) float    f32x4;

#define MFMA16 __builtin_amdgcn_mfma_f32_16x16x32_f16

// b32-granule XOR swizzle for epilogue A[64][128]: conflict-free row+column.
__device__ __forceinline__ int swz(int t, int e) {
  return t * EDIM + ((e & 96) | ((e ^ t) & 31));
}

// ---- W pre-convert: fragment-ordered f16 hi/lo planes in workspace ----
// frag idx -> (nt, ks, lane); lane holds B[k=ks*32+(lane>>4)*8+j][n=nt*16+(lane&15)]
// = Wr[n][k], scaled by 32 (hi) and 32*2048 (lo) to dodge f16 denormals.
__global__ __launch_bounds__(256)
void conv_w(const float* __restrict__ Wr,
            _Float16* __restrict__ wh, _Float16* __restrict__ wl) {
  const int idx  = (int)blockIdx.x * 256 + (int)threadIdx.x;  // 0..32767
  const int lane = idx & 63;
  const int ks   = (idx >> 6) & 63;
  const int nt   = idx >> 12;
  const int n    = nt * 16 + (lane & 15);
  const int k0   = ks * 32 + (lane >> 4) * 8;
  half8 h, l;
#pragma unroll
  for (int j = 0; j < 8; ++j) {
    const float w = Wr[(size_t)n * DDIM + k0 + j] * 32.0f;
    const _Float16 hh = (_Float16)w;
    h[j] = hh;
    l[j] = (_Float16)((w - (float)hh) * 2048.0f);
  }
  *(half8*)(wh + (size_t)idx * 8) = h;
  *(half8*)(wl + (size_t)idx * 8) = l;
}

__global__ __launch_bounds__(1024, 4)
void fused_router(const float* __restrict__ x,
                  const _Float16* __restrict__ wsh,
                  const _Float16* __restrict__ wsl,
                  const float* __restrict__ Wd,
                  const float* __restrict__ gamma,
                  const float* __restrict__ beta,
                  const float* __restrict__ rnn,
                  const float* __restrict__ gum,
                  float* __restrict__ outb,
                  float* __restrict__ outa) {
  // GEMM phase: 4-deep ring of 24 KB chunk buffers (96 KB total).
  //   buf layout: A frags [0,8K): mt*2048 + pl*1024 + inner
  //               B frags [8K,24K): nt*2048 + pl*1024 + lane*16
  // Counted-vmcnt pipeline: x + W issued 3 chunks ahead; s_waitcnt vmcnt(4)
  // before each raw s_barrier (4 = ops newer than the load that must land).
  // Epilogue overlays: A = bytes [0,32K), G4 = [32K,64K).
  __shared__ char smraw[98304];
  char* const sm = smraw;
  float* const A  = (float*)smraw;
  float* const G4 = (float*)(smraw + 32768);

  const int tid  = (int)threadIdx.x;
  const int wv   = __builtin_amdgcn_readfirstlane(tid >> 6);  // 0..15
  const int lane = tid & 63;
  const int t0   = (int)blockIdx.x * TOKT;

  // wave grid 2m x 4n x 2k: wave = 2 m-tiles x 2 n-tiles, half-K.
  const int mg   = (wv >> 2) & 1;
  const int ng   = wv & 3;
  const int kw   = wv >> 3;
  const int quad = lane >> 4;
  const int col  = lane & 15;

  // x staging: thread -> (token t_g, k-pair u); 8 B global -> cvt -> 2 b32 LDS
  const int t_g = tid >> 4;            // 0..63
  const int u   = tid & 15;            // k-pair within chunk (k0 = 2u)
  const float* xg = x + (size_t)(t0 + t_g) * DDIM + u * 2;
  const int xw_off = (t_g >> 4) * 2048
                   + ((u >> 2) * 16 + (t_g & 15)) * 16 + (u & 3) * 4;  // hi; +1024 lo

  // W staging: 16 waves <-> 16 (ntile, plane) segments, 1 glds (1 KB) each
  const int wnt = wv >> 1, wpl = wv & 1;
  const _Float16* wsrc = (wpl ? wsl : wsh) + (size_t)wnt * 32768 + (size_t)lane * 8;
  const int wdst = 8192 + wnt * 2048 + wpl * 1024;   // + ring-buffer base

  // fragment read offsets (within a ring buffer)
  const int aoff0 = (mg * 2 + 0) * 2048 + lane * 16;
  const int aoff1 = (mg * 2 + 1) * 2048 + lane * 16;
  const int boff0 = 8192 + (ng * 2 + 0) * 2048 + lane * 16;
  const int boff1 = 8192 + (ng * 2 + 1) * 2048 + lane * 16;

  f32x4 hh[2][2], cr[2][2];
#pragma unroll
  for (int mi = 0; mi < 2; ++mi)
#pragma unroll
    for (int ni = 0; ni < 2; ++ni) { hh[mi][ni] = (f32x4){0,0,0,0}; cr[mi][ni] = (f32x4){0,0,0,0}; }

  float2 rx0, rx1, rx2, rx3;

#define XLD(c)  (*(const float2*)(xg + (c) * KC))
#define GLDS(c, bsel) __builtin_amdgcn_global_load_lds( \
    (const __attribute__((address_space(1))) void*)(wsrc + (size_t)(c) * 512), \
    (__attribute__((address_space(3))) void*)(sm + (bsel) * BUFB + wdst), 16, 0, 0)
#define XCVT(c, RU) do { \
    const float v0_ = (RU).x, v1_ = (RU).y; \
    const _Float16 h0_ = (_Float16)v0_, h1_ = (_Float16)v1_; \
    const _Float16 l0_ = (_Float16)((v0_ - (float)h0_) * 2048.0f); \
    const _Float16 l1_ = (_Float16)((v1_ - (float)h1_) * 2048.0f); \
    char* wb_ = sm + ((c) & 3) * BUFB + xw_off; \
    *(half2v*)wb_ = (half2v){h0_, h1_}; \
    *(half2v*)(wb_ + 1024) = (half2v){l0_, l1_}; \
  } while (0)

#define ITER(c, RL, RU) do { \
    const int cf_ = ((c) + 3 < NCH) ? (c) + 3 : NCH - 1; \
    RL = XLD(cf_); \
    GLDS(cf_, ((c) + 3) & 3); \
    if ((c) + 1 < NCH) XCVT((c) + 1, RU); \
    if (((c) >> 5) == kw) { \
      const char* bb_ = sm + ((c) & 3) * BUFB; \
      const half8 ah0 = *(const half8*)(bb_ + aoff0); \
      const half8 al0 = *(const half8*)(bb_ + aoff0 + 1024); \
      const half8 ah1 = *(const half8*)(bb_ + aoff1); \
      const half8 al1 = *(const half8*)(bb_ + aoff1 + 1024); \
      const half8 bh0 = *(const half8*)(bb_ + boff0); \
      const half8 bl0 = *(const half8*)(bb_ + boff0 + 1024); \
      const half8 bh1 = *(const half8*)(bb_ + boff1); \
      const half8 bl1 = *(const half8*)(bb_ + boff1 + 1024); \
      hh[0][0] = MFMA16(ah0, bh0, hh[0][0], 0, 0, 0); \
      cr[0][0] = MFMA16(ah0, bl0, cr[0][0], 0, 0, 0); \
      cr[0][0] = MFMA16(al0, bh0, cr[0][0], 0, 0, 0); \
      hh[0][1] = MFMA16(ah0, bh1, hh[0][1], 0, 0, 0); \
      cr[0][1] = MFMA16(ah0, bl1, cr[0][1], 0, 0, 0); \
      cr[0][1] = MFMA16(al0, bh1, cr[0][1], 0, 0, 0); \
      hh[1][0] = MFMA16(ah1, bh0, hh[1][0], 0, 0, 0); \
      cr[1][0] = MFMA16(ah1, bl0, cr[1][0], 0, 0, 0); \
      cr[1][0] = MFMA16(al1, bh0, cr[1][0], 0, 0, 0); \
      hh[1][1] = MFMA16(ah1, bh1, hh[1][1], 0, 0, 0); \
      cr[1][1] = MFMA16(ah1, bl1, cr[1][1], 0, 0, 0); \
      cr[1][1] = MFMA16(al1, bh1, cr[1][1], 0, 0, 0); \
    } \
    asm volatile("s_waitcnt vmcnt(4) lgkmcnt(0)" ::: "memory"); \
    asm volatile("s_barrier" ::: "memory"); \
  } while (0)

  // ---- prologue: establish queue [x1,W1,x2,W2] + buf0 ready ----
  rx0 = XLD(0); GLDS(0, 0);
  rx1 = XLD(1); GLDS(1, 1);
  rx2 = XLD(2); GLDS(2, 2);
  XCVT(0, rx0);                        // compiler inserts the wait for rx0
  asm volatile("s_waitcnt vmcnt(4) lgkmcnt(0)" ::: "memory");
  asm volatile("s_barrier" ::: "memory");

  // ---- main loop: one raw barrier per chunk, vmcnt never drained ----
  for (int cc = 0; cc < NCH; cc += 4) {
    ITER(cc + 0, rx3, rx1);
    ITER(cc + 1, rx0, rx2);
    ITER(cc + 2, rx1, rx3);
    ITER(cc + 3, rx2, rx0);
  }
  asm volatile("s_waitcnt vmcnt(0) lgkmcnt(0)" ::: "memory");
  asm volatile("s_barrier" ::: "memory");

  // ---- k-split reduce + unscale + rnn into A ----
  // C/D layout: col = lane&15 -> e, row = quad*4+r -> token
  if (kw == 0) {
#pragma unroll
    for (int mi = 0; mi < 2; ++mi)
#pragma unroll
      for (int ni = 0; ni < 2; ++ni)
#pragma unroll
        for (int r = 0; r < 4; ++r) {
          const int t = (mg * 2 + mi) * 16 + quad * 4 + r;
          const int e = (ng * 2 + ni) * 16 + col;
          A[swz(t, e)] = hh[mi][ni][r] * (1.0f / 32.0f)
                       + cr[mi][ni][r] * (1.0f / 65536.0f);
        }
  }
  __syncthreads();
  if (kw == 1) {
#pragma unroll
    for (int mi = 0; mi < 2; ++mi)
#pragma unroll
      for (int ni = 0; ni < 2; ++ni) {
        const int e = (ng * 2 + ni) * 16 + col;
        const float rv = rnn[e];
#pragma unroll
        for (int r = 0; r < 4; ++r) {
          const int t = (mg * 2 + mi) * 16 + quad * 4 + r;
          A[swz(t, e)] += hh[mi][ni][r] * (1.0f / 32.0f)
                        + cr[mi][ni][r] * (1.0f / 65536.0f) + rv;
        }
      }
  }
  __syncthreads();

  // ---- LayerNorm + exact GELU: 4 tokens per wave; G -> G4 (float4-swizzled) ----
  const int e0 = wv * 8;                  // decoder e-mapping
  {
    const float gm0 = gamma[lane], gm1 = gamma[lane + 64];
    const float bt0 = beta[lane],  bt1 = beta[lane + 64];
    for (int tt = wv * 4; tt < wv * 4 + 4; ++tt) {
      const float v0 = A[swz(tt, lane)];
      const float v1 = A[swz(tt, lane + 64)];
      float s = v0 + v1;
#pragma unroll
      for (int m = 32; m; m >>= 1) s += __shfl_xor(s, m);
      const float mu = s * (1.0f / 128.0f);
      const float d0 = v0 - mu, d1 = v1 - mu;
      float q = d0 * d0 + d1 * d1;
#pragma unroll
      for (int m = 32; m; m >>= 1) q += __shfl_xor(q, m);
      const float rstd = 1.0f / sqrtf(q * (1.0f / 128.0f) + 1e-5f);
      const float h0v = d0 * rstd * gm0 + bt0;
      const float h1v = d1 * rstd * gm1 + bt1;
      const float g0 = 0.5f * h0v * (1.0f + erff(h0v * 0.70710678118654752f));
      const float g1 = 0.5f * h1v * (1.0f + erff(h1v * 0.70710678118654752f));
      const int e0a = lane, e1a = lane + 64;
      G4[(tt * 32 + (((e0a >> 2) ^ (tt & 31)))) * 4 + (e0a & 3)] = g0;
      G4[(tt * 32 + (((e1a >> 2) ^ (tt & 31)))) * 4 + (e1a & 3)] = g1;
    }
  }
  __syncthreads();

  // ---- decoder GEMM: wave = 8 h-rows x 64 tokens (lane = token) ----
  {
    float acc2[8];
#pragma unroll
    for (int j = 0; j < 8; ++j) acc2[j] = 0.0f;
    const float4* wd4 = (const float4*)(Wd + (size_t)e0 * EDIM);  // uniform
#pragma unroll 2
    for (int kg = 0; kg < EDIM / 4; ++kg) {
      const float4 gv = *(const float4*)&G4[(lane * 32 + (kg ^ (lane & 31))) * 4];
#pragma unroll
      for (int j = 0; j < 8; ++j) {
        const float4 w = wd4[(size_t)j * (EDIM / 4) + kg];
        acc2[j] = fmaf(gv.x, w.x,
                  fmaf(gv.y, w.y,
                  fmaf(gv.z, w.z,
                  fmaf(gv.w, w.w, acc2[j]))));
      }
    }
    __syncthreads();
#pragma unroll
    for (int j = 0; j < 8; ++j) A[swz(lane, e0 + j)] = acc2[j];
  }
  __syncthreads();

  // ---- gumbel-sigmoid, exact top-k (value then lower-index), output ----
  for (int tt = wv * 4; tt < wv * 4 + 4; ++tt) {
    const size_t T = (size_t)(t0 + tt);
    const float l0 = A[swz(tt, lane)];
    const float l1 = A[swz(tt, lane + 64)];
    const float gn0 = gum[T * HDIM + lane];
    const float gn1 = gum[T * HDIM + lane + 64];
    const float z0 = (l0 + gn0 + 3.0f) * 2.5f;
    const float z1 = (l1 + gn1 + 3.0f) * 2.5f;
    const float ba0 = 1.0f / (1.0f + expf(-z0));
    const float ba1 = 1.0f / (1.0f + expf(-z1));
    const unsigned ub0 = __float_as_uint(ba0);   // ba in (0,1]: bits monotone
    const unsigned ub1 = __float_as_uint(ba1);
    const int r0 = ba0 > 0.5f;                   // round: 0.5 -> 0
    const int r1 = ba1 > 0.5f;
    const int cnt = __popcll(__ballot(r0)) + __popcll(__ballot(r1));
    float bin0, bin1;
    if (cnt > 32) {
      unsigned v = 0u;                            // radix-select 32nd largest
#pragma unroll
      for (int b = 29; b >= 0; --b) {
        const unsigned cand = v | (1u << b);
        const int cc = __popcll(__ballot(ub0 >= cand)) + __popcll(__ballot(ub1 >= cand));
        if (cc >= 32) v = cand;
      }
      const int cgt = __popcll(__ballot(ub0 > v)) + __popcll(__ballot(ub1 > v));
      const int r = 32 - cgt;                     // tied slots; lower index wins
      const unsigned long long t0b = __ballot(ub0 == v);
      const unsigned long long t1b = __ballot(ub1 == v);
      const int n0 = __popcll(t0b);
      const unsigned long long mlt = (1ull << lane) - 1ull;
      const int rk0 = __popcll(t0b & mlt);
      const int rk1 = n0 + __popcll(t1b & mlt);
      bin0 = (ub0 > v || (ub0 == v && rk0 < r)) ? 1.0f : 0.0f;
      bin1 = (ub1 > v || (ub1 == v && rk1 < r)) ? 1.0f : 0.0f;
    } else if (cnt == 0) {
      float m = fmaxf(ba0, ba1);
#pragma unroll
      for (int mm = 32; mm; mm >>= 1) m = fmaxf(m, __shfl_xor(m, mm));
      const unsigned long long e0b = __ballot(ba0 == m);
      const unsigned long long e1b = __ballot(ba1 == m);
      const int hstar = e0b ? (__ffsll((unsigned long long)e0b) - 1)
                            : (64 + __ffsll((unsigned long long)e1b) - 1);
      bin0 = (lane == hstar) ? 1.0f : 0.0f;
      bin1 = (lane + 64 == hstar) ? 1.0f : 0.0f;
    } else {
      bin0 = r0 ? 1.0f : 0.0f;
      bin1 = r1 ? 1.0f : 0.0f;
    }
    outb[T * HDIM + lane]      = bin0;
    outb[T * HDIM + lane + 64] = bin1;
    outa[T * HDIM + lane]      = ba0;
    outa[T * HDIM + lane + 64] = ba1;
  }
}

extern "C" void kernel_launch(void* const* d_in, const int* in_sizes, int n_in,
                              void* d_out, int out_size, void* d_ws, size_t ws_size,
                              hipStream_t stream) {
  (void)in_sizes; (void)n_in; (void)ws_size; (void)out_size;
  const float* x   = (const float*)d_in[0];
  const float* Wr  = (const float*)d_in[1];
  const float* Wd  = (const float*)d_in[2];
  const float* gm  = (const float*)d_in[3];
  const float* bt  = (const float*)d_in[4];
  const float* rnn = (const float*)d_in[5];
  const float* gum = (const float*)d_in[6];
  float* outb = (float*)d_out;
  float* outa = outb + (size_t)NTOK * HDIM;   // tuple: (binary, binary_approx)

  _Float16* wh = (_Float16*)d_ws;             // 512 KB
  _Float16* wl = wh + (size_t)EDIM * DDIM;    // 512 KB

  conv_w<<<dim3(128), dim3(256), 0, stream>>>(Wr, wh, wl);
  fused_router<<<dim3(NTOK / TOKT), dim3(1024), 0, stream>>>(
      x, wh, wl, Wd, gm, bt, rnn, gum, outb, outa);
}